// Round 7
// baseline (288.916 us; speedup 1.0000x reference)
//
#include <hip/hip_runtime.h>
#include <hip/hip_bf16.h>
#include <math.h>

#define BB 4
#define NN 3000
#define FF 128
#define NP 3008         // padded rows per batch
#define CP 3072         // padded cols per batch (6 chunks x 512)
#define NKC 96          // 32-wide K chunks (96*32 = 3072)
#define NIT 188         // 16-row tiles (188*16 = 3008)

typedef __bf16 bf16x8 __attribute__((ext_vector_type(8)));
typedef __bf16 bf16x4 __attribute__((ext_vector_type(4)));
typedef float  f32x4  __attribute__((ext_vector_type(4)));

// ---------------- K1: row sums -> dis, and bf16 row-major copy of adj -----------
// One wave per padded row. Reads fp32 (coalesced float4), writes bf16x4 (8 B/lane,
// coalesced). Pad rows (i>=NN) and pad cols (>=NN) are written as zeros so k_agg
// needs no bounds checks at all.
__global__ __launch_bounds__(256) void k_deg(const float* __restrict__ adj,
                                             __bf16* __restrict__ adjh,
                                             float* __restrict__ dis) {
    int wid  = (blockIdx.x * 256 + threadIdx.x) >> 6;   // 0 .. BB*NP-1
    int lane = threadIdx.x & 63;
    int b = wid / NP, i = wid % NP;
    bool rowok = i < NN;
    const float* row = adj + ((size_t)b * NN + (rowok ? i : 0)) * NN;
    __bf16* drow = adjh + (size_t)wid * CP;
    float s = 0.f;
    for (int c = lane; c < CP / 4; c += 64) {
        int col = c * 4;
        float4 v = {0.f, 0.f, 0.f, 0.f};
        if (rowok && col < NN) v = *(const float4*)(row + col);   // NN%4==0
        s += (v.x + v.y) + (v.z + v.w);
        bf16x4 h;
        h[0] = (__bf16)v.x; h[1] = (__bf16)v.y;
        h[2] = (__bf16)v.z; h[3] = (__bf16)v.w;
        *(bf16x4*)(drow + col) = h;
    }
    for (int off = 32; off > 0; off >>= 1) s += __shfl_down(s, off, 64);
    if (lane == 0 && rowok) dis[b * NN + i] = 1.0f / sqrtf(s + 1.0f);
}

// ---------------- K2: pack xs = dis_k * x[k][f] into MFMA B-fragment order ------
// xpk[b][nt][kc][lane][8], lane = (f%16) + 16*quad, k = kc*32 + quad*8 + j.
__global__ __launch_bounds__(256) void k_xpk(const float* __restrict__ x,
                                             const float* __restrict__ dis,
                                             __bf16* __restrict__ xpk) {
    int b  = blockIdx.y, kc = blockIdx.x;
    int t  = threadIdx.x, w = t >> 6, l = t & 63;
    int m  = l & 15, q = l >> 4;
    #pragma unroll
    for (int h = 0; h < 2; ++h) {
        int nt = w + h * 4;
        int f  = nt * 16 + m;
        bf16x8 v;
        #pragma unroll
        for (int j = 0; j < 8; ++j) {
            int k = kc * 32 + q * 8 + j;
            float val = 0.f;
            if (k < NN) val = dis[b * NN + k] * x[((size_t)b * NN + k) * FF + f];
            v[j] = (__bf16)val;
        }
        *(bf16x8*)(xpk + ((size_t)(b * 8 + nt) * NKC + kc) * 512 + l * 8) = v;
    }
}

// ---------------- K2b: pack theta into MFMA B-fragment order --------------------
__global__ __launch_bounds__(256) void k_thpk(const float* __restrict__ theta,
                                              __bf16* __restrict__ thpk) {
    int kc = blockIdx.x;
    int t  = threadIdx.x, w = t >> 6, l = t & 63;
    int m  = l & 15, q = l >> 4;
    #pragma unroll
    for (int h = 0; h < 2; ++h) {
        int nt = w + h * 4;
        bf16x8 v;
        #pragma unroll
        for (int j = 0; j < 8; ++j) {
            int k = kc * 32 + q * 8 + j;
            v[j] = (__bf16)theta[k * FF + nt * 16 + m];
        }
        *(bf16x8*)(thpk + ((size_t)(nt * 4 + kc)) * 512 + l * 8) = v;
    }
}

// ---------------- K3 (fused): out = beta*(support@theta) + (1-beta)*support ------
// support = (1-alpha)*hi + alpha*h0,  hi_i = dis_i*(adj_i . xs) + dis_i^2 * x_i
// Staging: global_load_lds (16 B/lane) from bf16 adjh; each wave fills one
// contiguous 1024-B LDS row per issue (wave-uniform base + lane*16). Double
// buffer, one barrier per 512-wide chunk; chunk c+1 issued before chunk c's
// MFMA loop so the pre-barrier vmcnt drain is overlapped by compute.
__global__ __launch_bounds__(256) void k_agg(const __bf16* __restrict__ adjh,
                                             const __bf16* __restrict__ xpk,
                                             const __bf16* __restrict__ thpk,
                                             const float* __restrict__ x,
                                             const float* __restrict__ h0,
                                             const float* __restrict__ dis,
                                             float* __restrict__ out,
                                             const float* __restrict__ alpha_p,
                                             const float* __restrict__ lamda_p,
                                             const int* __restrict__ l_p) {
    __shared__ __bf16 tile[2][16][520];   // 512 cols + 8 pad
    __shared__ __bf16 stile[16][136];
    const int b  = blockIdx.y;
    const int it = blockIdx.x;
    const int i0 = it * 16;
    const int t  = threadIdx.x, w = t >> 6, l = t & 63;
    const int m  = l & 15, quad = l >> 4;
    const int n0 = w * 32;
    const __bf16* B0 = xpk + ((size_t)(b * 8 + 2 * w) * NKC) * 512 + l * 8;
    const __bf16* B1 = B0 + (size_t)NKC * 512;
    f32x4 acc0 = {0.f, 0.f, 0.f, 0.f};
    f32x4 acc1 = {0.f, 0.f, 0.f, 0.f};

    // wave w stages rows {w, 4+w, 8+w, 12+w}; lane l covers cols [l*8, l*8+8)
    auto issue = [&](int c, int cb) {
        #pragma unroll
        for (int i = 0; i < 4; ++i) {
            int row = i * 4 + w;
            const __bf16* g = adjh + ((size_t)(b * NP) + i0 + row) * CP + c * 512 + l * 8;
            __builtin_amdgcn_global_load_lds(
                (const __attribute__((address_space(1))) unsigned int*)g,
                (__attribute__((address_space(3))) unsigned int*)&tile[cb][row][0],
                16, 0, 0);
        }
    };

    issue(0, 0);
    __syncthreads();
    for (int c = 0; c < 6; ++c) {
        int cb = c & 1;
        if (c < 5) issue(c + 1, cb ^ 1);
        #pragma unroll 4
        for (int kcl = 0; kcl < 16; ++kcl) {
            int kc = c * 16 + kcl;
            bf16x8 a  = *(const bf16x8*)&tile[cb][m][kcl * 32 + quad * 8];
            bf16x8 b0 = *(const bf16x8*)(B0 + (size_t)kc * 512);
            bf16x8 b1 = *(const bf16x8*)(B1 + (size_t)kc * 512);
            acc0 = __builtin_amdgcn_mfma_f32_16x16x32_bf16(a, b0, acc0, 0, 0, 0);
            acc1 = __builtin_amdgcn_mfma_f32_16x16x32_bf16(a, b1, acc1, 0, 0, 0);
        }
        __syncthreads();
    }

    // ---- epilogue: support values; stage tile in A-layout (bf16) ----
    const float alpha = *alpha_p;
    const float beta  = logf(*lamda_p / (float)(*l_p) + 1.0f);
    float s0v[4], s1v[4];
    #pragma unroll
    for (int r = 0; r < 4; ++r) {
        int row  = quad * 4 + r;
        int irow = i0 + row;
        float s0 = 0.f, s1 = 0.f;
        if (irow < NN) {
            float  di   = dis[b * NN + irow];
            size_t base = ((size_t)b * NN + irow) * FF;
            int c0 = n0 + m, c1 = n0 + 16 + m;
            s0 = (1.f - alpha) * (di * acc0[r] + di * di * x[base + c0]) + alpha * h0[base + c0];
            s1 = (1.f - alpha) * (di * acc1[r] + di * di * x[base + c1]) + alpha * h0[base + c1];
        }
        s0v[r] = s0; s1v[r] = s1;
        stile[row][n0 + m]      = (__bf16)s0;
        stile[row][n0 + 16 + m] = (__bf16)s1;
    }
    __syncthreads();
    // ---- theta matmul on the 16x128 support tile ----
    f32x4 o0 = {0.f, 0.f, 0.f, 0.f};
    f32x4 o1 = {0.f, 0.f, 0.f, 0.f};
    const __bf16* T0 = thpk + (size_t)(2 * w * 4) * 512 + l * 8;
    const __bf16* T1 = T0 + 4 * 512;
    #pragma unroll
    for (int kc = 0; kc < 4; ++kc) {
        bf16x8 a   = *(const bf16x8*)&stile[m][kc * 32 + quad * 8];
        bf16x8 tb0 = *(const bf16x8*)(T0 + (size_t)kc * 512);
        bf16x8 tb1 = *(const bf16x8*)(T1 + (size_t)kc * 512);
        o0 = __builtin_amdgcn_mfma_f32_16x16x32_bf16(a, tb0, o0, 0, 0, 0);
        o1 = __builtin_amdgcn_mfma_f32_16x16x32_bf16(a, tb1, o1, 0, 0, 0);
    }
    const float omb = 1.f - beta;
    #pragma unroll
    for (int r = 0; r < 4; ++r) {
        int irow = i0 + quad * 4 + r;
        if (irow < NN) {
            size_t base = ((size_t)b * NN + irow) * FF;
            out[base + n0 + m]      = beta * o0[r] + omb * s0v[r];
            out[base + n0 + 16 + m] = beta * o1[r] + omb * s1v[r];
        }
    }
}

extern "C" void kernel_launch(void* const* d_in, const int* in_sizes, int n_in,
                              void* d_out, int out_size, void* d_ws, size_t ws_size,
                              hipStream_t stream) {
    const float* x      = (const float*)d_in[0];
    const float* adj    = (const float*)d_in[1];
    const float* h0     = (const float*)d_in[2];
    const float* theta  = (const float*)d_in[3];
    const float* lamda  = (const float*)d_in[4];
    const float* alpha  = (const float*)d_in[5];
    const int*   l      = (const int*)d_in[6];
    float* out = (float*)d_out;

    char*   ws   = (char*)d_ws;
    float*  dis  = (float*)ws;                 // 48,000 B
    __bf16* xpk  = (__bf16*)(ws + 65536);      // 4*8*96*512*2 = 3,145,728 B
    __bf16* thpk = (__bf16*)(ws + 3276800);    // 32,768 B
    __bf16* adjh = (__bf16*)(ws + 4 * 1024 * 1024);   // 4*3008*3072*2 = 73,924,608 B

    k_deg<<<dim3(BB * NP / 4), 256, 0, stream>>>(adj, adjh, dis);
    k_thpk<<<dim3(4), 256, 0, stream>>>(theta, thpk);
    k_xpk<<<dim3(NKC, BB), 256, 0, stream>>>(x, dis, xpk);
    k_agg<<<dim3(NIT, BB), 256, 0, stream>>>(adjh, xpk, thpk, x, h0, dis, out,
                                             alpha, lamda, l);
}

// Round 8
// 275.230 us; speedup vs baseline: 1.0497x; 1.0497x over previous
//
#include <hip/hip_runtime.h>
#include <hip/hip_bf16.h>
#include <math.h>

#define BB 4
#define NN 3000
#define FF 128
#define NKC 96          // 32-wide K chunks (96*32 = 3072), 6 big chunks x 16
#define NIT 188         // 16-row tiles (188*16 = 3008)
#define TS  532         // LDS tile row stride: 266 dw = 10 mod 32 -> <=2-way banks

typedef __bf16 bf16x8 __attribute__((ext_vector_type(8)));
typedef __bf16 bf16x4 __attribute__((ext_vector_type(4)));
typedef __bf16 bf16x8a __attribute__((ext_vector_type(8), aligned(8)));
typedef __bf16 bf16x4a __attribute__((ext_vector_type(4), aligned(4)));
typedef float  f32x4  __attribute__((ext_vector_type(4)));

// ---------------- K1: dis[b*NN+i] = 1/sqrt(1 + sum_j adj[b,i,j]) ----------------
__global__ __launch_bounds__(256) void k_deg(const float* __restrict__ adj,
                                             float* __restrict__ dis) {
    int wid  = (blockIdx.x * 256 + threadIdx.x) >> 6;
    int lane = threadIdx.x & 63;
    if (wid >= BB * NN) return;
    const float4* row = (const float4*)(adj + (size_t)wid * NN);
    float s = 0.f;
    for (int c = lane; c < NN / 4; c += 64) {
        float4 v = row[c];
        s += (v.x + v.y) + (v.z + v.w);
    }
    for (int off = 32; off > 0; off >>= 1) s += __shfl_down(s, off, 64);
    if (lane == 0) dis[wid] = 1.0f / sqrtf(s + 1.0f);
}

// ---------------- K2: pack xs = dis_k * x[k][f] into MFMA B-fragment order ------
__global__ __launch_bounds__(256) void k_xpk(const float* __restrict__ x,
                                             const float* __restrict__ dis,
                                             __bf16* __restrict__ xpk) {
    int b  = blockIdx.y, kc = blockIdx.x;
    int t  = threadIdx.x, w = t >> 6, l = t & 63;
    int m  = l & 15, q = l >> 4;
    #pragma unroll
    for (int h = 0; h < 2; ++h) {
        int nt = w + h * 4;
        int f  = nt * 16 + m;
        bf16x8 v;
        #pragma unroll
        for (int j = 0; j < 8; ++j) {
            int k = kc * 32 + q * 8 + j;
            float val = 0.f;
            if (k < NN) val = dis[b * NN + k] * x[((size_t)b * NN + k) * FF + f];
            v[j] = (__bf16)val;
        }
        *(bf16x8*)(xpk + ((size_t)(b * 8 + nt) * NKC + kc) * 512 + l * 8) = v;
    }
}

// ---------------- K2b: pack theta into MFMA B-fragment order --------------------
__global__ __launch_bounds__(256) void k_thpk(const float* __restrict__ theta,
                                              __bf16* __restrict__ thpk) {
    int kc = blockIdx.x;
    int t  = threadIdx.x, w = t >> 6, l = t & 63;
    int m  = l & 15, q = l >> 4;
    #pragma unroll
    for (int h = 0; h < 2; ++h) {
        int nt = w + h * 4;
        bf16x8 v;
        #pragma unroll
        for (int j = 0; j < 8; ++j) {
            int k = kc * 32 + q * 8 + j;
            v[j] = (__bf16)theta[k * FF + nt * 16 + m];
        }
        *(bf16x8*)(thpk + ((size_t)(nt * 4 + kc)) * 512 + l * 8) = v;
    }
}

// ---------------- K3 (fused): out = beta*(support@theta) + (1-beta)*support ------
// R6 structure (dbuf BK=512, 1 barrier/chunk) with two fixes:
//  - LDS tile stride 532 (266 dw = 10 mod 32): A-frag reads <=2-way banked (free)
//    instead of 8-way at stride 520; 8-B-aligned b64 pairs.
//  - 1-D grid + XCD swizzle: batch b pinned to XCDs {2b,2b+1} so each XCD's L2
//    holds one 3 MB xpk slice instead of thrashing on all four.
__global__ __launch_bounds__(256) void k_agg(const float* __restrict__ adj,
                                             const __bf16* __restrict__ xpk,
                                             const __bf16* __restrict__ thpk,
                                             const float* __restrict__ x,
                                             const float* __restrict__ h0,
                                             const float* __restrict__ dis,
                                             float* __restrict__ out,
                                             const float* __restrict__ alpha_p,
                                             const float* __restrict__ lamda_p,
                                             const int* __restrict__ l_p) {
    __shared__ __bf16 tile[2][16][TS];
    __shared__ __bf16 stile[16][140];
    const int id = blockIdx.x;
    const int b  = (id >> 1) & 3;                 // XCD pair per batch
    const int it = (id >> 3) * 2 + (id & 1);
    const int i0 = it * 16;
    const int t  = threadIdx.x, w = t >> 6, l = t & 63;
    const int m  = l & 15, quad = l >> 4;
    const int n0 = w * 32;
    const __bf16* B0 = xpk + ((size_t)(b * 8 + 2 * w) * NKC) * 512 + l * 8;
    const __bf16* B1 = B0 + (size_t)NKC * 512;
    f32x4 acc0 = {0.f, 0.f, 0.f, 0.f};
    f32x4 acc1 = {0.f, 0.f, 0.f, 0.f};

    float4 pu[4], pv[4];
    // wave w stages rows {w, 4+w, 8+w, 12+w}; lane l covers cols [l*8, l*8+8)
    auto load_chunk = [&](int c) {
        #pragma unroll
        for (int i = 0; i < 4; ++i) {
            int row  = i * 4 + w;
            int irow = i0 + row;
            int col  = c * 512 + l * 8;
            float4 u = {0.f, 0.f, 0.f, 0.f}, v = {0.f, 0.f, 0.f, 0.f};
            if (irow < NN && col < NN) {   // NN%8==0
                const float* p = adj + ((size_t)b * NN + irow) * NN + col;
                u = *(const float4*)p;
                v = *(const float4*)(p + 4);
            }
            pu[i] = u; pv[i] = v;
        }
    };
    auto store_chunk = [&](int cb) {
        #pragma unroll
        for (int i = 0; i < 4; ++i) {
            int row = i * 4 + w;
            bf16x8a s;
            s[0] = (__bf16)pu[i].x; s[1] = (__bf16)pu[i].y;
            s[2] = (__bf16)pu[i].z; s[3] = (__bf16)pu[i].w;
            s[4] = (__bf16)pv[i].x; s[5] = (__bf16)pv[i].y;
            s[6] = (__bf16)pv[i].z; s[7] = (__bf16)pv[i].w;
            *(bf16x8a*)&tile[cb][row][l * 8] = s;
        }
    };

    load_chunk(0);
    store_chunk(0);
    __syncthreads();
    for (int c = 0; c < 6; ++c) {
        int cb = c & 1;
        if (c < 5) load_chunk(c + 1);
        #pragma unroll 4
        for (int kcl = 0; kcl < 16; ++kcl) {
            int kc = c * 16 + kcl;
            bf16x8 a = *(const bf16x8a*)&tile[cb][m][kcl * 32 + quad * 8];
            bf16x8 b0 = *(const bf16x8*)(B0 + (size_t)kc * 512);
            bf16x8 b1 = *(const bf16x8*)(B1 + (size_t)kc * 512);
            acc0 = __builtin_amdgcn_mfma_f32_16x16x32_bf16(a, b0, acc0, 0, 0, 0);
            acc1 = __builtin_amdgcn_mfma_f32_16x16x32_bf16(a, b1, acc1, 0, 0, 0);
        }
        if (c < 5) store_chunk(cb ^ 1);
        __syncthreads();
    }

    // ---- epilogue: support values; stage tile in A-layout (bf16) ----
    const float alpha = *alpha_p;
    const float beta  = logf(*lamda_p / (float)(*l_p) + 1.0f);
    float s0v[4], s1v[4];
    #pragma unroll
    for (int r = 0; r < 4; ++r) {
        int row  = quad * 4 + r;
        int irow = i0 + row;
        float s0 = 0.f, s1 = 0.f;
        if (irow < NN) {
            float  di   = dis[b * NN + irow];
            size_t base = ((size_t)b * NN + irow) * FF;
            int c0 = n0 + m, c1 = n0 + 16 + m;
            s0 = (1.f - alpha) * (di * acc0[r] + di * di * x[base + c0]) + alpha * h0[base + c0];
            s1 = (1.f - alpha) * (di * acc1[r] + di * di * x[base + c1]) + alpha * h0[base + c1];
        }
        s0v[r] = s0; s1v[r] = s1;
        stile[row][n0 + m]      = (__bf16)s0;
        stile[row][n0 + 16 + m] = (__bf16)s1;
    }
    __syncthreads();
    // ---- theta matmul on the 16x128 support tile ----
    f32x4 o0 = {0.f, 0.f, 0.f, 0.f};
    f32x4 o1 = {0.f, 0.f, 0.f, 0.f};
    const __bf16* T0 = thpk + (size_t)(2 * w * 4) * 512 + l * 8;
    const __bf16* T1 = T0 + 4 * 512;
    #pragma unroll
    for (int kc = 0; kc < 4; ++kc) {
        bf16x4a alo = *(const bf16x4a*)&stile[m][kc * 32 + quad * 8];
        bf16x4a ahi = *(const bf16x4a*)&stile[m][kc * 32 + quad * 8 + 4];
        bf16x8 a = __builtin_shufflevector(alo, ahi, 0, 1, 2, 3, 4, 5, 6, 7);
        bf16x8 tb0 = *(const bf16x8*)(T0 + (size_t)kc * 512);
        bf16x8 tb1 = *(const bf16x8*)(T1 + (size_t)kc * 512);
        o0 = __builtin_amdgcn_mfma_f32_16x16x32_bf16(a, tb0, o0, 0, 0, 0);
        o1 = __builtin_amdgcn_mfma_f32_16x16x32_bf16(a, tb1, o1, 0, 0, 0);
    }
    const float omb = 1.f - beta;
    #pragma unroll
    for (int r = 0; r < 4; ++r) {
        int irow = i0 + quad * 4 + r;
        if (irow < NN) {
            size_t base = ((size_t)b * NN + irow) * FF;
            out[base + n0 + m]      = beta * o0[r] + omb * s0v[r];
            out[base + n0 + 16 + m] = beta * o1[r] + omb * s1v[r];
        }
    }
}

extern "C" void kernel_launch(void* const* d_in, const int* in_sizes, int n_in,
                              void* d_out, int out_size, void* d_ws, size_t ws_size,
                              hipStream_t stream) {
    const float* x      = (const float*)d_in[0];
    const float* adj    = (const float*)d_in[1];
    const float* h0     = (const float*)d_in[2];
    const float* theta  = (const float*)d_in[3];
    const float* lamda  = (const float*)d_in[4];
    const float* alpha  = (const float*)d_in[5];
    const int*   l      = (const int*)d_in[6];
    float* out = (float*)d_out;

    char*   ws   = (char*)d_ws;
    float*  dis  = (float*)ws;                 // 48,000 B
    __bf16* xpk  = (__bf16*)(ws + 65536);      // 4*8*96*512*2 = 3,145,728 B
    __bf16* thpk = (__bf16*)(ws + 3276800);    // 32,768 B

    k_deg<<<dim3((BB * NN) / 4), 256, 0, stream>>>(adj, dis);
    k_thpk<<<dim3(4), 256, 0, stream>>>(theta, thpk);
    k_xpk<<<dim3(NKC, BB), 256, 0, stream>>>(x, dis, xpk);
    k_agg<<<dim3(NIT * BB), 256, 0, stream>>>(adj, xpk, thpk, x, h0, dis, out,
                                              alpha, lamda, l);
}